// Round 9
// baseline (138.350 us; speedup 1.0000x reference)
//
#include <hip/hip_runtime.h>
#include <hip/hip_bf16.h>
#include <cstdint>

#define CH 128
#define NB 512          // coarse buckets (128 nodes each); N < 65536 for packing
#define SCHUNK 4096     // edges per scatter/hist block

typedef __attribute__((ext_vector_type(8))) short short8;
typedef __attribute__((ext_vector_type(4))) float f32x4;

union FragU {
  uint4 u;
  short8 s;
  ushort h[8];
};

// ---------------- bf16 helpers ----------------
__device__ __forceinline__ float bf_lo(uint32_t u) { return __uint_as_float(u << 16); }
__device__ __forceinline__ float bf_hi(uint32_t u) { return __uint_as_float(u & 0xffff0000u); }
__device__ __forceinline__ uint32_t f2bf(float f) {  // RNE, result in low 16
  uint32_t u = __float_as_uint(f);
  u += 0x7fff + ((u >> 16) & 1);
  return u >> 16;
}

// ---------------- CSR build: contention-free counting sort ----------------
// 1) per-block LDS histogram -> counts[bucket * nblk + blk]; extra blocks do W pre-pack.
__global__ __launch_bounds__(256) void k_histw(const int* __restrict__ dst, int* __restrict__ counts,
                                               int E, int nblk,
                                               const float* __restrict__ W1, const float* __restrict__ W2,
                                               ushort* __restrict__ wbuf) {
  int blk = blockIdx.x;
  if (blk >= nblk) {
    // ---- W pre-pack into MFMA fragment order (hi/lo bf16) ----
    int bb = blk - nblk;             // 0..127
    int which = bb >> 6;
    int idx = (bb & 63) * 256 + threadIdx.x;  // 0..16383
    const float* W = which ? W2 : W1;
    ushort* hi = wbuf + which * 32768;
    ushort* lo = hi + 16384;
    int k = idx >> 7, n = idx & 127;
    float w = W[idx];
    uint32_t hb = f2bf(w);
    uint32_t lb = f2bf(w - bf_lo(hb));
    int j = n >> 4, t = k >> 5, ln = (n & 15) | (((k >> 3) & 3) << 4), i = k & 7;
    int p = (j * 4 + t) * 512 + ln * 8 + i;
    hi[p] = (ushort)hb;
    lo[p] = (ushort)lb;
    return;
  }
  __shared__ int sh[NB];
  int t = threadIdx.x;
  for (int i = t; i < NB; i += 256) sh[i] = 0;
  __syncthreads();
  int base = blk * SCHUNK, lim = min(base + SCHUNK, E);
  for (int i = base + t; i < lim; i += 256) atomicAdd(&sh[dst[i] >> 7], 1);
  __syncthreads();
  for (int i = t; i < NB; i += 256) counts[i * nblk + blk] = sh[i];
}

// 2a) scan within 1024-blocks (coalesced, multi-block)
__global__ __launch_bounds__(1024) void k_scan1(const int* __restrict__ in, int* __restrict__ excl,
                                                int* __restrict__ blocksum, int n) {
  __shared__ int sd[1024];
  int tid = threadIdx.x;
  int i = blockIdx.x * 1024 + tid;
  int v = (i < n) ? in[i] : 0;
  int x = v;
  sd[tid] = x;
  __syncthreads();
  for (int off = 1; off < 1024; off <<= 1) {
    int t = (tid >= off) ? sd[tid - off] : 0;
    __syncthreads();
    x += t;
    sd[tid] = x;
    __syncthreads();
  }
  if (i < n) excl[i] = x - v;
  if (tid == 1023) blocksum[blockIdx.x] = x;
}

// 2b) scan block sums (1 block, 128 threads; nsb <= 128)
__global__ void k_scan2b(int* __restrict__ bs, int nb) {
  __shared__ int sh[128];
  int t = threadIdx.x;
  int v = (t < nb) ? bs[t] : 0;
  sh[t] = v;
  __syncthreads();
  for (int off = 1; off < 128; off <<= 1) {
    int add = (t >= off) ? sh[t - off] : 0;
    __syncthreads();
    sh[t] += add;
    __syncthreads();
  }
  if (t < nb) bs[t] = sh[t] - v;
}

// 2c) add block offsets in place; emit bbase[b] = excl[b*nblk], bbase[NB] = E
__global__ __launch_bounds__(256) void k_scan3b(int* __restrict__ excl, const int* __restrict__ boff,
                                                int* __restrict__ bbase, int total, int nblk, int E) {
  int i = blockIdx.x * 256 + threadIdx.x;
  if (i < total) {
    int val = excl[i] + boff[i >> 10];
    excl[i] = val;
    if (i % nblk == 0) bbase[i / nblk] = val;
  }
  if (i == 0) bbase[NB] = E;
}

// 3) scatter: block base from scanned counts, local rank via LDS atomics (no global atomics)
__global__ __launch_bounds__(256) void k_scatter3(const int* __restrict__ src, const int* __restrict__ dst,
                                                  const int* __restrict__ excl, uint32_t* __restrict__ packed,
                                                  int E, int nblk) {
  __shared__ int lcur[NB];
  int t = threadIdx.x, blk = blockIdx.x;
  for (int i = t; i < NB; i += 256) lcur[i] = excl[i * nblk + blk];
  __syncthreads();
  int base = blk * SCHUNK, lim = min(base + SCHUNK, E);
  for (int i = base + t; i < lim; i += 256) {
    int d = dst[i], s = src[i];
    int slot = atomicAdd(&lcur[d >> 7], 1);
    packed[slot] = (uint32_t)s | ((uint32_t)(d & 127) << 16);
  }
}

// 4) per-bucket local CSR build; emits csr_src, row_ptr, dinv
__global__ __launch_bounds__(256) void k_bucket(const uint32_t* __restrict__ packed, const int* __restrict__ bbase,
                                                int* __restrict__ csr_src, int* __restrict__ row_ptr,
                                                float* __restrict__ dinv, int N, int E, int nb) {
  __shared__ int hist[128];
  __shared__ int scan[128];
  __shared__ int cur[128];
  int b = blockIdx.x;
  int t = threadIdx.x;
  int base = bbase[b], end = bbase[b + 1];
  if (t < 128) hist[t] = 0;
  __syncthreads();
  for (int i = base + t; i < end; i += 256)
    atomicAdd(&hist[packed[i] >> 16], 1);
  __syncthreads();
  int v = (t < 128) ? hist[t] : 0;
  if (t < 128) scan[t] = v;
  __syncthreads();
  for (int off = 1; off < 128; off <<= 1) {
    int add = (t < 128 && t >= off) ? scan[t - off] : 0;
    __syncthreads();
    if (t < 128) scan[t] += add;
    __syncthreads();
  }
  if (t < 128) {
    int excl = scan[t] - v;
    cur[t] = excl;
    int node = b * 128 + t;
    if (node < N) {
      row_ptr[node] = base + excl;
      dinv[node] = rsqrtf((float)(v + 1));  // +1 self-loop
    }
    if (b == nb - 1 && t == 0) row_ptr[N] = E;
  }
  __syncthreads();
  for (int i = base + t; i < end; i += 256) {
    uint32_t p = packed[i];
    int slot = atomicAdd(&cur[p >> 16], 1);
    csr_src[base + slot] = (int)(p & 0xffffu);
  }
}

// ---------------- MFMA GEMM: h'[r] = (A[r] @ W) * dinv[r], bf16 out, split lo/hi tables ----
__global__ __launch_bounds__(256) void k_gemm_mfma(const float* __restrict__ A,
                                                   const ushort* __restrict__ wpack,
                                                   const float* __restrict__ dinv,
                                                   ushort* __restrict__ Cl, ushort* __restrict__ Chh,
                                                   int n) {
  const int lane = threadIdx.x & 63;
  const int gwave = (blockIdx.x * 256 + threadIdx.x) >> 6;
  const int rb = gwave * 32;
  if (rb >= n) return;
  const int lrow = lane & 15, lgrp = lane >> 4;
  const uint4* whi4 = (const uint4*)wpack;
  const uint4* wlo4 = (const uint4*)(wpack + 16384);

  const int r0 = rb + lrow, r1 = rb + 16 + lrow;
  const bool v0 = r0 < n, v1 = r1 < n;
  const int rc0 = v0 ? r0 : 0, rc1 = v1 ? r1 : 0;

  f32x4 acc0[8] = {};
  f32x4 acc1[8] = {};
  const uint4 zz = make_uint4(0, 0, 0, 0);

#pragma unroll
  for (int t = 0; t < 4; ++t) {
    FragU a0h, a0l, a1h, a1l;
    const float* ap0 = A + (size_t)rc0 * CH + t * 32 + lgrp * 8;
    const float* ap1 = A + (size_t)rc1 * CH + t * 32 + lgrp * 8;
    float4 xa = *(const float4*)ap0, xb = *(const float4*)(ap0 + 4);
    float4 ya = *(const float4*)ap1, yb = *(const float4*)(ap1 + 4);
    float xv[8] = {xa.x, xa.y, xa.z, xa.w, xb.x, xb.y, xb.z, xb.w};
    float yv[8] = {ya.x, ya.y, ya.z, ya.w, yb.x, yb.y, yb.z, yb.w};
#pragma unroll
    for (int i = 0; i < 8; ++i) {
      uint32_t h0 = f2bf(xv[i]);
      a0h.h[i] = (ushort)h0;
      a0l.h[i] = (ushort)f2bf(xv[i] - bf_lo(h0));
      uint32_t h1 = f2bf(yv[i]);
      a1h.h[i] = (ushort)h1;
      a1l.h[i] = (ushort)f2bf(yv[i] - bf_lo(h1));
    }
    if (!v0) { a0h.u = zz; a0l.u = zz; }
    if (!v1) { a1h.u = zz; a1l.u = zz; }
#pragma unroll
    for (int j = 0; j < 8; ++j) {
      FragU wh, wl;
      wh.u = whi4[(j * 4 + t) * 64 + lane];
      wl.u = wlo4[(j * 4 + t) * 64 + lane];
      acc0[j] = __builtin_amdgcn_mfma_f32_16x16x32_bf16(wh.s, a0h.s, acc0[j], 0, 0, 0);
      acc0[j] = __builtin_amdgcn_mfma_f32_16x16x32_bf16(wl.s, a0h.s, acc0[j], 0, 0, 0);
      acc0[j] = __builtin_amdgcn_mfma_f32_16x16x32_bf16(wh.s, a0l.s, acc0[j], 0, 0, 0);
      acc1[j] = __builtin_amdgcn_mfma_f32_16x16x32_bf16(wh.s, a1h.s, acc1[j], 0, 0, 0);
      acc1[j] = __builtin_amdgcn_mfma_f32_16x16x32_bf16(wl.s, a1h.s, acc1[j], 0, 0, 0);
      acc1[j] = __builtin_amdgcn_mfma_f32_16x16x32_bf16(wh.s, a1l.s, acc1[j], 0, 0, 0);
    }
  }

  if (v0) {
    float dv = dinv[r0];
#pragma unroll
    for (int j = 0; j < 8; ++j) {
      uint2 o;
      o.x = f2bf(acc0[j][0] * dv) | (f2bf(acc0[j][1] * dv) << 16);
      o.y = f2bf(acc0[j][2] * dv) | (f2bf(acc0[j][3] * dv) << 16);
      ushort* hp = (j < 4) ? Cl : Chh;
      *(uint2*)&hp[(size_t)r0 * 64 + (j & 3) * 16 + lgrp * 4] = o;
    }
  }
  if (v1) {
    float dv = dinv[r1];
#pragma unroll
    for (int j = 0; j < 8; ++j) {
      uint2 o;
      o.x = f2bf(acc1[j][0] * dv) | (f2bf(acc1[j][1] * dv) << 16);
      o.y = f2bf(acc1[j][2] * dv) | (f2bf(acc1[j][3] * dv) << 16);
      ushort* hp = (j < 4) ? Cl : Chh;
      *(uint2*)&hp[(size_t)r1 * 64 + (j & 3) * 16 + lgrp * 4] = o;
    }
  }
}

// ---------------- half-channel aggregation core ----------------
// hh = half-table (N x 32 dwords = N x 64 bf16). Lanes 0-31 take even edges,
// lanes 32-63 odd edges; lane covers 2 channels (dword hl). csr indices are
// loaded at WAVE-UNIFORM addresses (scalar path), selected per-lane by eh.
// Result (a0,a1) = full sum for channels 2*hl, 2*hl+1 (valid in all lanes).
__device__ __forceinline__ void agg_half(const uint32_t* __restrict__ hh,
                                         const int* __restrict__ row_ptr,
                                         const int* __restrict__ csr,
                                         int v, int hl, int eh,
                                         float& r0, float& r1) {
  float sel0 = (eh == 0) ? 1.f : 0.f;  // count self/tail once (in low half)
  uint32_t su = hh[(size_t)v * 32 + hl];
  float a0 = bf_lo(su) * sel0, a1 = bf_hi(su) * sel0;
  int j = __builtin_amdgcn_readfirstlane(row_ptr[v]);
  int end = __builtin_amdgcn_readfirstlane(row_ptr[v + 1]);
  int cnt = end - j;
  int npair = cnt >> 1;
  int p = 0;
  for (; p + 3 < npair; p += 4) {
    int sE0 = csr[j + 2 * p + 0], sO0 = csr[j + 2 * p + 1];
    int sE1 = csr[j + 2 * p + 2], sO1 = csr[j + 2 * p + 3];
    int sE2 = csr[j + 2 * p + 4], sO2 = csr[j + 2 * p + 5];
    int sE3 = csr[j + 2 * p + 6], sO3 = csr[j + 2 * p + 7];
    int s0 = eh ? sO0 : sE0;
    int s1 = eh ? sO1 : sE1;
    int s2 = eh ? sO2 : sE2;
    int s3 = eh ? sO3 : sE3;
    uint32_t u0 = hh[(size_t)s0 * 32 + hl];
    uint32_t u1 = hh[(size_t)s1 * 32 + hl];
    uint32_t u2 = hh[(size_t)s2 * 32 + hl];
    uint32_t u3 = hh[(size_t)s3 * 32 + hl];
    a0 += bf_lo(u0); a1 += bf_hi(u0);
    a0 += bf_lo(u1); a1 += bf_hi(u1);
    a0 += bf_lo(u2); a1 += bf_hi(u2);
    a0 += bf_lo(u3); a1 += bf_hi(u3);
  }
  for (; p < npair; ++p) {
    int sE = csr[j + 2 * p], sO = csr[j + 2 * p + 1];
    int s = eh ? sO : sE;
    uint32_t u = hh[(size_t)s * 32 + hl];
    a0 += bf_lo(u); a1 += bf_hi(u);
  }
  if (cnt & 1) {
    int sT = __builtin_amdgcn_readfirstlane(csr[end - 1]);
    uint32_t u = hh[(size_t)sT * 32 + hl];
    a0 += bf_lo(u) * sel0; a1 += bf_hi(u) * sel0;
  }
  a0 += __shfl_xor(a0, 32, 64);
  a1 += __shfl_xor(a1, 32, 64);
  r0 = a0;
  r1 = a1;
}

// ---------------- fused: agg1(+b1,relu) -> LDS -> @W2 -> h2' = h2*dinv (bf16, split) ----
// block = 256 threads = 4 waves; 32 nodes per block; lo-phase then hi-phase.
__global__ __launch_bounds__(256) void k_fused(const uint32_t* __restrict__ h1l, const uint32_t* __restrict__ h1h,
                                               const int* __restrict__ row_ptr,
                                               const int* __restrict__ csr, const float* __restrict__ dinv,
                                               const float* __restrict__ b1,
                                               const ushort* __restrict__ wpack2,
                                               ushort* __restrict__ h2l, ushort* __restrict__ h2h, int N) {
  __shared__ uint32_t sy[32 * 64];  // 32 rows x 128 bf16, word-swizzled
  const int w = threadIdx.x >> 6;
  const int lane = threadIdx.x & 63;
  const int hl = lane & 31;
  const int eh = lane >> 5;
  const int vb = blockIdx.x * 32;

  // ---- agg phase: lo channels for the wave's 8 nodes, then hi channels ----
#pragma unroll
  for (int ph = 0; ph < 2; ++ph) {
    const uint32_t* hh = ph ? h1h : h1l;
    float2 bb = *(const float2*)&b1[ph * 64 + 2 * hl];
    for (int q = 0; q < 8; ++q) {
      int lv = w * 8 + q;
      int v = vb + lv;
      uint32_t d = 0;
      if (v < N) {
        float a0, a1;
        agg_half(hh, row_ptr, csr, v, hl, eh, a0, a1);
        float dv = dinv[v];
        float o0 = fmaxf(fmaf(dv, a0, bb.x), 0.f);
        float o1 = fmaxf(fmaf(dv, a1, bb.y), 0.f);
        d = f2bf(o0) | (f2bf(o1) << 16);
      }
      if (eh == 0) {
        int widx = ph * 32 + hl;
        sy[lv * 64 + (widx ^ ((lv & 7) << 2))] = d;
      }
    }
  }
  __syncthreads();

  // ---- MFMA phase: 32x128 @ W2; wave w covers output cols [w*32, w*32+32) ----
  const int lrow = lane & 15, lgrp = lane >> 4;
  const uint4* whi4 = (const uint4*)wpack2;
  const uint4* wlo4 = (const uint4*)(wpack2 + 16384);

  FragU af[2][4];
#pragma unroll
  for (int rt = 0; rt < 2; ++rt) {
#pragma unroll
    for (int t = 0; t < 4; ++t) {
      int row = rt * 16 + lrow;
      int grp = (t * 4 + lgrp) ^ (row & 7);
      af[rt][t].u = *(const uint4*)&sy[row * 64 + grp * 4];
    }
  }

  f32x4 acc[2][2] = {};
#pragma unroll
  for (int jj = 0; jj < 2; ++jj) {
    int j = w * 2 + jj;
#pragma unroll
    for (int t = 0; t < 4; ++t) {
      FragU wh, wl;
      wh.u = whi4[(j * 4 + t) * 64 + lane];
      wl.u = wlo4[(j * 4 + t) * 64 + lane];
      acc[0][jj] = __builtin_amdgcn_mfma_f32_16x16x32_bf16(wh.s, af[0][t].s, acc[0][jj], 0, 0, 0);
      acc[0][jj] = __builtin_amdgcn_mfma_f32_16x16x32_bf16(wl.s, af[0][t].s, acc[0][jj], 0, 0, 0);
      acc[1][jj] = __builtin_amdgcn_mfma_f32_16x16x32_bf16(wh.s, af[1][t].s, acc[1][jj], 0, 0, 0);
      acc[1][jj] = __builtin_amdgcn_mfma_f32_16x16x32_bf16(wl.s, af[1][t].s, acc[1][jj], 0, 0, 0);
    }
  }

#pragma unroll
  for (int rt = 0; rt < 2; ++rt) {
    int r = vb + rt * 16 + lrow;
    if (r < N) {
      float dvr = dinv[r];
#pragma unroll
      for (int jj = 0; jj < 2; ++jj) {
        int j = w * 2 + jj;
        uint2 o;
        o.x = f2bf(acc[rt][jj][0] * dvr) | (f2bf(acc[rt][jj][1] * dvr) << 16);
        o.y = f2bf(acc[rt][jj][2] * dvr) | (f2bf(acc[rt][jj][3] * dvr) << 16);
        ushort* hp = (j < 4) ? h2l : h2h;
        *(uint2*)&hp[(size_t)r * 64 + (j & 3) * 16 + lgrp * 4] = o;
      }
    }
  }
}

// ---------------- final aggregation (one channel half per dispatch) ----------------
template <int HALF>
__global__ __launch_bounds__(256) void k_agg2(const uint32_t* __restrict__ hh, const int* __restrict__ row_ptr,
                                              const int* __restrict__ csr, const float* __restrict__ dinv,
                                              const float* __restrict__ b2, float* __restrict__ out, int n) {
  int vw = (blockIdx.x * 256 + threadIdx.x) >> 6;
  int lane = threadIdx.x & 63;
  if (vw >= n) return;
  int v = __builtin_amdgcn_readfirstlane(vw);
  int hl = lane & 31;
  int eh = lane >> 5;
  float a0, a1;
  agg_half(hh, row_ptr, csr, v, hl, eh, a0, a1);
  float dv = dinv[v];
  float2 bb = *(const float2*)&b2[HALF * 64 + 2 * hl];
  float o0 = fmaxf(fmaf(dv, a0, bb.x), 0.f);
  float o1 = fmaxf(fmaf(dv, a1, bb.y), 0.f);
  if (eh == 0)
    *(float2*)&out[(size_t)v * CH + HALF * 64 + 2 * hl] = make_float2(o0, o1);
}

// ---------------- launch ----------------

extern "C" void kernel_launch(void* const* d_in, const int* in_sizes, int n_in,
                              void* d_out, int out_size, void* d_ws, size_t ws_size,
                              hipStream_t stream) {
  const float* x  = (const float*)d_in[0];
  const int*   ei = (const int*)d_in[1];
  const float* W1 = (const float*)d_in[2];
  const float* b1 = (const float*)d_in[3];
  const float* W2 = (const float*)d_in[4];
  const float* b2 = (const float*)d_in[5];
  float* out = (float*)d_out;

  const int N = in_sizes[0] / CH;
  const int E = in_sizes[1] / 2;
  const int* src = ei;
  const int* dst = ei + E;
  const int nb = (N + 127) / 128;              // used coarse buckets (<= NB)
  const int nblk = (E + SCHUNK - 1) / SCHUNK;  // hist/scatter blocks
  const int total = NB * nblk;                 // counts array size
  const int nsb = (total + 1023) / 1024;       // scan blocks (<=128)

  char* ws = (char*)d_ws;
  size_t off = 0;
  auto alloc = [&](size_t bytes) -> void* {
    void* p = ws + off;
    off += (bytes + 255) & ~(size_t)255;
    return p;
  };
  int*      counts  = (int*)alloc((size_t)total * 4);     // scanned in place
  int*      blocksum= (int*)alloc(128 * 4);
  int*      bbase   = (int*)alloc((NB + 1) * 4);
  uint32_t* packed  = (uint32_t*)alloc((size_t)E * 4);
  int*      row_ptr = (int*)alloc((size_t)(N + 1) * 4);
  int*      csr_src = (int*)alloc((size_t)E * 4);
  float*    dinv    = (float*)alloc((size_t)N * 4);
  ushort*   wpack   = (ushort*)alloc(4 * 16384 * 2);       // [hi1|lo1|hi2|lo2]
  ushort*   h1l     = (ushort*)alloc((size_t)N * 64 * 2);  // bf16, dinv-scaled, ch 0-63
  ushort*   h1h     = (ushort*)alloc((size_t)N * 64 * 2);  // ch 64-127
  ushort*   h2l     = (ushort*)alloc((size_t)N * 64 * 2);
  ushort*   h2h     = (ushort*)alloc((size_t)N * 64 * 2);
  (void)ws_size;

  k_histw<<<nblk + 128, 256, 0, stream>>>(dst, counts, E, nblk, W1, W2, wpack);
  k_scan1<<<nsb, 1024, 0, stream>>>(counts, counts, blocksum, total);
  k_scan2b<<<1, 128, 0, stream>>>(blocksum, nsb);
  k_scan3b<<<(total + 255) / 256, 256, 0, stream>>>(counts, blocksum, bbase, total, nblk, E);
  k_scatter3<<<nblk, 256, 0, stream>>>(src, dst, counts, packed, E, nblk);
  k_bucket<<<nb, 256, 0, stream>>>(packed, bbase, csr_src, row_ptr, dinv, N, E, nb);

  const int waves = (N + 31) / 32;
  const int gG = (waves + 3) / 4;
  const int gF = (N + 31) / 32;
  const int gA = (N + 3) / 4;

  k_gemm_mfma<<<gG, 256, 0, stream>>>(x, wpack, dinv, h1l, h1h, N);
  k_fused<<<gF, 256, 0, stream>>>((const uint32_t*)h1l, (const uint32_t*)h1h, row_ptr, csr_src,
                                  dinv, b1, wpack + 32768, h2l, h2h, N);
  k_agg2<0><<<gA, 256, 0, stream>>>((const uint32_t*)h2l, row_ptr, csr_src, dinv, b2, out, N);
  k_agg2<1><<<gA, 256, 0, stream>>>((const uint32_t*)h2h, row_ptr, csr_src, dinv, b2, out, N);
}

// Round 10
// 119.441 us; speedup vs baseline: 1.1583x; 1.1583x over previous
//
#include <hip/hip_runtime.h>
#include <hip/hip_bf16.h>
#include <cstdint>

#define CH 128
#define NB 512          // coarse buckets (128 nodes each); N < 65536 for packing
#define SCHUNK 4096     // edges per scatter/hist block (nblk must stay <= 256 for k_scanbkt)

typedef __attribute__((ext_vector_type(8))) short short8;
typedef __attribute__((ext_vector_type(4))) float f32x4;

union FragU {
  uint4 u;
  short8 s;
  ushort h[8];
};

// ---------------- bf16 helpers ----------------
__device__ __forceinline__ float bf_lo(uint32_t u) { return __uint_as_float(u << 16); }
__device__ __forceinline__ float bf_hi(uint32_t u) { return __uint_as_float(u & 0xffff0000u); }
__device__ __forceinline__ uint32_t f2bf(float f) {  // RNE, result in low 16
  uint32_t u = __float_as_uint(f);
  u += 0x7fff + ((u >> 16) & 1);
  return u >> 16;
}

// ---------------- CSR build: contention-free counting sort ----------------
// 1) per-block LDS histogram -> counts[bucket * nblk + blk] + bucket totals (btotal
//    pre-zeroed by memset); extra blocks do W pre-pack.
__global__ __launch_bounds__(256) void k_histw(const int* __restrict__ dst, int* __restrict__ counts,
                                               int* __restrict__ btotal, int E, int nblk,
                                               const float* __restrict__ W1, const float* __restrict__ W2,
                                               ushort* __restrict__ wbuf) {
  int blk = blockIdx.x;
  if (blk >= nblk) {
    // ---- W pre-pack into MFMA fragment order (hi/lo bf16) ----
    int bb = blk - nblk;             // 0..127
    int which = bb >> 6;
    int idx = (bb & 63) * 256 + threadIdx.x;  // 0..16383
    const float* W = which ? W2 : W1;
    ushort* hi = wbuf + which * 32768;
    ushort* lo = hi + 16384;
    int k = idx >> 7, n = idx & 127;
    float w = W[idx];
    uint32_t hb = f2bf(w);
    uint32_t lb = f2bf(w - bf_lo(hb));
    int j = n >> 4, t = k >> 5, ln = (n & 15) | (((k >> 3) & 3) << 4), i = k & 7;
    int p = (j * 4 + t) * 512 + ln * 8 + i;
    hi[p] = (ushort)hb;
    lo[p] = (ushort)lb;
    return;
  }
  __shared__ int sh[NB];
  int t = threadIdx.x;
  for (int i = t; i < NB; i += 256) sh[i] = 0;
  __syncthreads();
  int base = blk * SCHUNK, lim = min(base + SCHUNK, E);
  for (int i = base + t; i < lim; i += 256) atomicAdd(&sh[dst[i] >> 7], 1);
  __syncthreads();
  for (int i = t; i < NB; i += 256) {
    counts[i * nblk + blk] = sh[i];
    if (sh[i]) atomicAdd(&btotal[i], sh[i]);
  }
}

// 2) one block per bucket: redundant scan of 512 bucket totals -> bucket base,
//    then local scan of this bucket's nblk per-block counts (in place).
__global__ __launch_bounds__(256) void k_scanbkt(int* __restrict__ counts, const int* __restrict__ btotal,
                                                 int* __restrict__ bbase, int nblk, int E) {
  __shared__ int sp[256];
  int b = blockIdx.x, t = threadIdx.x;
  int v0 = btotal[2 * t], v1 = btotal[2 * t + 1];
  sp[t] = v0 + v1;
  __syncthreads();
  for (int off = 1; off < 256; off <<= 1) {
    int add = (t >= off) ? sp[t - off] : 0;
    __syncthreads();
    sp[t] += add;
    __syncthreads();
  }
  int g = b >> 1;
  int base = ((g > 0) ? sp[g - 1] : 0) + ((b & 1) ? btotal[b - 1] : 0);
  __syncthreads();
  int c = (t < nblk) ? counts[b * nblk + t] : 0;
  sp[t] = c;
  __syncthreads();
  for (int off = 1; off < 256; off <<= 1) {
    int add = (t >= off) ? sp[t - off] : 0;
    __syncthreads();
    sp[t] += add;
    __syncthreads();
  }
  int excl = sp[t] - c;
  if (t < nblk) counts[b * nblk + t] = base + excl;
  if (t == 0) bbase[b] = base;
  if (b == 0 && t == 0) bbase[NB] = E;
}

// 3) scatter: block base from scanned counts, local rank via LDS atomics (no global atomics)
__global__ __launch_bounds__(256) void k_scatter3(const int* __restrict__ src, const int* __restrict__ dst,
                                                  const int* __restrict__ excl, uint32_t* __restrict__ packed,
                                                  int E, int nblk) {
  __shared__ int lcur[NB];
  int t = threadIdx.x, blk = blockIdx.x;
  for (int i = t; i < NB; i += 256) lcur[i] = excl[i * nblk + blk];
  __syncthreads();
  int base = blk * SCHUNK, lim = min(base + SCHUNK, E);
  for (int i = base + t; i < lim; i += 256) {
    int d = dst[i], s = src[i];
    int slot = atomicAdd(&lcur[d >> 7], 1);
    packed[slot] = (uint32_t)s | ((uint32_t)(d & 127) << 16);
  }
}

// 4) per-bucket local CSR build; emits csr_src, row_ptr, dinv
__global__ __launch_bounds__(256) void k_bucket(const uint32_t* __restrict__ packed, const int* __restrict__ bbase,
                                                int* __restrict__ csr_src, int* __restrict__ row_ptr,
                                                float* __restrict__ dinv, int N, int E, int nb) {
  __shared__ int hist[128];
  __shared__ int scan[128];
  __shared__ int cur[128];
  int b = blockIdx.x;
  int t = threadIdx.x;
  int base = bbase[b], end = bbase[b + 1];
  if (t < 128) hist[t] = 0;
  __syncthreads();
  for (int i = base + t; i < end; i += 256)
    atomicAdd(&hist[packed[i] >> 16], 1);
  __syncthreads();
  int v = (t < 128) ? hist[t] : 0;
  if (t < 128) scan[t] = v;
  __syncthreads();
  for (int off = 1; off < 128; off <<= 1) {
    int add = (t < 128 && t >= off) ? scan[t - off] : 0;
    __syncthreads();
    if (t < 128) scan[t] += add;
    __syncthreads();
  }
  if (t < 128) {
    int excl = scan[t] - v;
    cur[t] = excl;
    int node = b * 128 + t;
    if (node < N) {
      row_ptr[node] = base + excl;
      dinv[node] = rsqrtf((float)(v + 1));  // +1 self-loop
    }
    if (b == nb - 1 && t == 0) row_ptr[N] = E;
  }
  __syncthreads();
  for (int i = base + t; i < end; i += 256) {
    uint32_t p = packed[i];
    int slot = atomicAdd(&cur[p >> 16], 1);
    csr_src[base + slot] = (int)(p & 0xffffu);
  }
}

// ---------------- MFMA GEMM: h'[r] = (A[r] @ W) * dinv[r], bf16 out ----------------
__global__ __launch_bounds__(256) void k_gemm_mfma(const float* __restrict__ A,
                                                   const ushort* __restrict__ wpack,
                                                   const float* __restrict__ dinv,
                                                   ushort* __restrict__ Cp, int n) {
  const int lane = threadIdx.x & 63;
  const int gwave = (blockIdx.x * 256 + threadIdx.x) >> 6;
  const int rb = gwave * 32;
  if (rb >= n) return;
  const int lrow = lane & 15, lgrp = lane >> 4;
  const uint4* whi4 = (const uint4*)wpack;
  const uint4* wlo4 = (const uint4*)(wpack + 16384);

  const int r0 = rb + lrow, r1 = rb + 16 + lrow;
  const bool v0 = r0 < n, v1 = r1 < n;
  const int rc0 = v0 ? r0 : 0, rc1 = v1 ? r1 : 0;

  f32x4 acc0[8] = {};
  f32x4 acc1[8] = {};
  const uint4 zz = make_uint4(0, 0, 0, 0);

#pragma unroll
  for (int t = 0; t < 4; ++t) {
    FragU a0h, a0l, a1h, a1l;
    const float* ap0 = A + (size_t)rc0 * CH + t * 32 + lgrp * 8;
    const float* ap1 = A + (size_t)rc1 * CH + t * 32 + lgrp * 8;
    float4 xa = *(const float4*)ap0, xb = *(const float4*)(ap0 + 4);
    float4 ya = *(const float4*)ap1, yb = *(const float4*)(ap1 + 4);
    float xv[8] = {xa.x, xa.y, xa.z, xa.w, xb.x, xb.y, xb.z, xb.w};
    float yv[8] = {ya.x, ya.y, ya.z, ya.w, yb.x, yb.y, yb.z, yb.w};
#pragma unroll
    for (int i = 0; i < 8; ++i) {
      uint32_t h0 = f2bf(xv[i]);
      a0h.h[i] = (ushort)h0;
      a0l.h[i] = (ushort)f2bf(xv[i] - bf_lo(h0));
      uint32_t h1 = f2bf(yv[i]);
      a1h.h[i] = (ushort)h1;
      a1l.h[i] = (ushort)f2bf(yv[i] - bf_lo(h1));
    }
    if (!v0) { a0h.u = zz; a0l.u = zz; }
    if (!v1) { a1h.u = zz; a1l.u = zz; }
#pragma unroll
    for (int j = 0; j < 8; ++j) {
      FragU wh, wl;
      wh.u = whi4[(j * 4 + t) * 64 + lane];
      wl.u = wlo4[(j * 4 + t) * 64 + lane];
      acc0[j] = __builtin_amdgcn_mfma_f32_16x16x32_bf16(wh.s, a0h.s, acc0[j], 0, 0, 0);
      acc0[j] = __builtin_amdgcn_mfma_f32_16x16x32_bf16(wl.s, a0h.s, acc0[j], 0, 0, 0);
      acc0[j] = __builtin_amdgcn_mfma_f32_16x16x32_bf16(wh.s, a0l.s, acc0[j], 0, 0, 0);
      acc1[j] = __builtin_amdgcn_mfma_f32_16x16x32_bf16(wh.s, a1h.s, acc1[j], 0, 0, 0);
      acc1[j] = __builtin_amdgcn_mfma_f32_16x16x32_bf16(wl.s, a1h.s, acc1[j], 0, 0, 0);
      acc1[j] = __builtin_amdgcn_mfma_f32_16x16x32_bf16(wh.s, a1l.s, acc1[j], 0, 0, 0);
    }
  }

  if (v0) {
    float dv = dinv[r0];
#pragma unroll
    for (int j = 0; j < 8; ++j) {
      uint2 o;
      o.x = f2bf(acc0[j][0] * dv) | (f2bf(acc0[j][1] * dv) << 16);
      o.y = f2bf(acc0[j][2] * dv) | (f2bf(acc0[j][3] * dv) << 16);
      *(uint2*)&Cp[(size_t)r0 * CH + j * 16 + lgrp * 4] = o;
    }
  }
  if (v1) {
    float dv = dinv[r1];
#pragma unroll
    for (int j = 0; j < 8; ++j) {
      uint2 o;
      o.x = f2bf(acc1[j][0] * dv) | (f2bf(acc1[j][1] * dv) << 16);
      o.y = f2bf(acc1[j][2] * dv) | (f2bf(acc1[j][3] * dv) << 16);
      *(uint2*)&Cp[(size_t)r1 * CH + j * 16 + lgrp * 4] = o;
    }
  }
}

// ---------------- aggregation core: acc = h'[v] + sum_{s in N(v)} h'[s] ----------------
// full wave per node, 2 adjacent channels per lane; scalar (wave-uniform) index loads.
__device__ __forceinline__ void agg_node(const uint32_t* __restrict__ hp, const int* __restrict__ row_ptr,
                                         const int* __restrict__ csr, int v, int lane,
                                         float& a0, float& a1) {
  uint32_t self = hp[(size_t)v * 64 + lane];
  float acc0 = bf_lo(self), acc1 = bf_hi(self);
  int j = __builtin_amdgcn_readfirstlane(row_ptr[v]);
  int end = __builtin_amdgcn_readfirstlane(row_ptr[v + 1]);
  for (; j + 7 < end; j += 8) {
    int s[8];
#pragma unroll
    for (int k = 0; k < 8; ++k) s[k] = csr[j + k];
    uint32_t u[8];
#pragma unroll
    for (int k = 0; k < 8; ++k) u[k] = hp[(size_t)s[k] * 64 + lane];
#pragma unroll
    for (int k = 0; k < 8; ++k) { acc0 += bf_lo(u[k]); acc1 += bf_hi(u[k]); }
  }
  for (; j < end; ++j) {
    uint32_t u = hp[(size_t)csr[j] * 64 + lane];
    acc0 += bf_lo(u); acc1 += bf_hi(u);
  }
  a0 = acc0;
  a1 = acc1;
}

// ---------------- fused: agg1(+b1,relu) -> LDS -> @W2 -> h2' = h2*dinv (bf16) ----------------
// block = 256 threads = 4 waves; 32 nodes per block claimed dynamically (LDS ticket)
// to remove static-assignment tail imbalance. LDS XOR-swizzled 32x128 bf16.
__global__ __launch_bounds__(256) void k_fused(const uint32_t* __restrict__ h1p, const int* __restrict__ row_ptr,
                                               const int* __restrict__ csr, const float* __restrict__ dinv,
                                               const float* __restrict__ b1,
                                               const ushort* __restrict__ wpack2,
                                               ushort* __restrict__ h2, int N) {
  __shared__ uint32_t sy[32 * 64];  // 32 rows x 128 bf16, word-swizzled
  __shared__ int ctr;
  const int lane = threadIdx.x & 63;
  const int vb = blockIdx.x * 32;
  float2 bb = *(const float2*)&b1[2 * lane];
  if (threadIdx.x == 0) ctr = 0;
  __syncthreads();

  // ---- agg phase: waves claim nodes dynamically ----
  for (;;) {
    int q0 = 0;
    if (lane == 0) q0 = atomicAdd(&ctr, 1);
    int q = __shfl(q0, 0, 64);
    if (q >= 32) break;
    int v = vb + q;
    uint32_t packed = 0;
    if (v < N) {
      float a0, a1;
      agg_node(h1p, row_ptr, csr, v, lane, a0, a1);
      float dv = dinv[v];
      float o0 = fmaxf(fmaf(dv, a0, bb.x), 0.f);
      float o1 = fmaxf(fmaf(dv, a1, bb.y), 0.f);
      packed = f2bf(o0) | (f2bf(o1) << 16);
    }
    sy[q * 64 + (lane ^ ((q & 7) << 2))] = packed;
  }
  __syncthreads();

  // ---- MFMA phase: 32x128 @ W2; wave w covers output cols [w*32, w*32+32) ----
  const int w = threadIdx.x >> 6;
  const int lrow = lane & 15, lgrp = lane >> 4;
  const uint4* whi4 = (const uint4*)wpack2;
  const uint4* wlo4 = (const uint4*)(wpack2 + 16384);

  FragU af[2][4];
#pragma unroll
  for (int rt = 0; rt < 2; ++rt) {
#pragma unroll
    for (int t = 0; t < 4; ++t) {
      int row = rt * 16 + lrow;
      int grp = (t * 4 + lgrp) ^ (row & 7);
      af[rt][t].u = *(const uint4*)&sy[row * 64 + grp * 4];
    }
  }

  f32x4 acc[2][2] = {};
#pragma unroll
  for (int jj = 0; jj < 2; ++jj) {
    int j = w * 2 + jj;
#pragma unroll
    for (int t = 0; t < 4; ++t) {
      FragU wh, wl;
      wh.u = whi4[(j * 4 + t) * 64 + lane];
      wl.u = wlo4[(j * 4 + t) * 64 + lane];
      acc[0][jj] = __builtin_amdgcn_mfma_f32_16x16x32_bf16(wh.s, af[0][t].s, acc[0][jj], 0, 0, 0);
      acc[0][jj] = __builtin_amdgcn_mfma_f32_16x16x32_bf16(wl.s, af[0][t].s, acc[0][jj], 0, 0, 0);
      acc[1][jj] = __builtin_amdgcn_mfma_f32_16x16x32_bf16(wh.s, af[1][t].s, acc[1][jj], 0, 0, 0);
      acc[1][jj] = __builtin_amdgcn_mfma_f32_16x16x32_bf16(wl.s, af[1][t].s, acc[1][jj], 0, 0, 0);
    }
  }

#pragma unroll
  for (int rt = 0; rt < 2; ++rt) {
    int r = vb + rt * 16 + lrow;
    if (r < N) {
      float dvr = dinv[r];
#pragma unroll
      for (int jj = 0; jj < 2; ++jj) {
        int j = w * 2 + jj;
        uint2 o;
        o.x = f2bf(acc[rt][jj][0] * dvr) | (f2bf(acc[rt][jj][1] * dvr) << 16);
        o.y = f2bf(acc[rt][jj][2] * dvr) | (f2bf(acc[rt][jj][3] * dvr) << 16);
        *(uint2*)&h2[(size_t)r * CH + j * 16 + lgrp * 4] = o;
      }
    }
  }
}

// ---------------- final aggregation: out[v] = relu(dv * (sum h2'[s] + h2'[v]) + b2), fp32 ----
__global__ __launch_bounds__(256) void k_agg2(const uint32_t* __restrict__ h2p, const int* __restrict__ row_ptr,
                                              const int* __restrict__ csr, const float* __restrict__ dinv,
                                              const float* __restrict__ b2, float* __restrict__ out, int n) {
  int v = (blockIdx.x * 256 + threadIdx.x) >> 6;
  int lane = threadIdx.x & 63;
  if (v >= n) return;
  v = __builtin_amdgcn_readfirstlane(v);
  float a0, a1;
  agg_node(h2p, row_ptr, csr, v, lane, a0, a1);
  float dv = dinv[v];
  float2 bb = *(const float2*)&b2[2 * lane];
  float o0 = fmaxf(fmaf(dv, a0, bb.x), 0.f);
  float o1 = fmaxf(fmaf(dv, a1, bb.y), 0.f);
  ((float2*)out)[(size_t)v * 64 + lane] = make_float2(o0, o1);
}

// ---------------- launch ----------------

extern "C" void kernel_launch(void* const* d_in, const int* in_sizes, int n_in,
                              void* d_out, int out_size, void* d_ws, size_t ws_size,
                              hipStream_t stream) {
  const float* x  = (const float*)d_in[0];
  const int*   ei = (const int*)d_in[1];
  const float* W1 = (const float*)d_in[2];
  const float* b1 = (const float*)d_in[3];
  const float* W2 = (const float*)d_in[4];
  const float* b2 = (const float*)d_in[5];
  float* out = (float*)d_out;

  const int N = in_sizes[0] / CH;
  const int E = in_sizes[1] / 2;
  const int* src = ei;
  const int* dst = ei + E;
  const int nb = (N + 127) / 128;              // used coarse buckets (<= NB)
  const int nblk = (E + SCHUNK - 1) / SCHUNK;  // hist/scatter blocks (<= 256)
  const int total = NB * nblk;                 // counts array size

  char* ws = (char*)d_ws;
  size_t off = 0;
  auto alloc = [&](size_t bytes) -> void* {
    void* p = ws + off;
    off += (bytes + 255) & ~(size_t)255;
    return p;
  };
  int*      counts  = (int*)alloc((size_t)total * 4);     // scanned in place
  int*      btotal  = (int*)alloc(NB * 4);
  int*      bbase   = (int*)alloc((NB + 1) * 4);
  uint32_t* packed  = (uint32_t*)alloc((size_t)E * 4);
  int*      row_ptr = (int*)alloc((size_t)(N + 1) * 4);
  int*      csr_src = (int*)alloc((size_t)E * 4);
  float*    dinv    = (float*)alloc((size_t)N * 4);
  ushort*   wpack   = (ushort*)alloc(4 * 16384 * 2);       // [hi1|lo1|hi2|lo2]
  ushort*   h1      = (ushort*)alloc((size_t)N * CH * 2);  // bf16, dinv-scaled
  ushort*   h2      = (ushort*)alloc((size_t)N * CH * 2);  // bf16, dinv-scaled
  (void)ws_size;

  hipMemsetAsync(btotal, 0, NB * 4, stream);  // re-zero every call (accumulated by atomics)

  k_histw<<<nblk + 128, 256, 0, stream>>>(dst, counts, btotal, E, nblk, W1, W2, wpack);
  k_scanbkt<<<NB, 256, 0, stream>>>(counts, btotal, bbase, nblk, E);
  k_scatter3<<<nblk, 256, 0, stream>>>(src, dst, counts, packed, E, nblk);
  k_bucket<<<nb, 256, 0, stream>>>(packed, bbase, csr_src, row_ptr, dinv, N, E, nb);

  const int waves = (N + 31) / 32;
  const int gG = (waves + 3) / 4;
  const int gF = (N + 31) / 32;
  const int gA = (N + 3) / 4;

  k_gemm_mfma<<<gG, 256, 0, stream>>>(x, wpack, dinv, h1, N);
  k_fused<<<gF, 256, 0, stream>>>((const uint32_t*)h1, row_ptr, csr_src, dinv, b1,
                                  wpack + 32768, h2, N);
  k_agg2<<<gA, 256, 0, stream>>>((const uint32_t*)h2, row_ptr, csr_src, dinv, b2, out, N);
}

// Round 11
// 114.798 us; speedup vs baseline: 1.2052x; 1.0404x over previous
//
#include <hip/hip_runtime.h>
#include <hip/hip_bf16.h>
#include <cstdint>

#define CH 128
#define NB 512          // coarse buckets (128 nodes each); N < 65536 for packing
#define SCHUNK 4096     // edges per scatter/hist block

typedef __attribute__((ext_vector_type(8))) short short8;
typedef __attribute__((ext_vector_type(4))) float f32x4;

union FragU {
  uint4 u;
  short8 s;
  ushort h[8];
};

// ---------------- bf16 helpers ----------------
__device__ __forceinline__ float bf_lo(uint32_t u) { return __uint_as_float(u << 16); }
__device__ __forceinline__ float bf_hi(uint32_t u) { return __uint_as_float(u & 0xffff0000u); }
__device__ __forceinline__ uint32_t f2bf(float f) {  // RNE, result in low 16
  uint32_t u = __float_as_uint(f);
  u += 0x7fff + ((u >> 16) & 1);
  return u >> 16;
}

// ---------------- CSR build: contention-free counting sort ----------------
// 1) per-block LDS histogram -> counts[bucket * nblk + blk]; extra blocks do W pre-pack.
__global__ __launch_bounds__(256) void k_histw(const int* __restrict__ dst, int* __restrict__ counts,
                                               int E, int nblk,
                                               const float* __restrict__ W1, const float* __restrict__ W2,
                                               ushort* __restrict__ wbuf) {
  int blk = blockIdx.x;
  if (blk >= nblk) {
    // ---- W pre-pack into MFMA fragment order (hi/lo bf16) ----
    int bb = blk - nblk;             // 0..127
    int which = bb >> 6;
    int idx = (bb & 63) * 256 + threadIdx.x;  // 0..16383
    const float* W = which ? W2 : W1;
    ushort* hi = wbuf + which * 32768;
    ushort* lo = hi + 16384;
    int k = idx >> 7, n = idx & 127;
    float w = W[idx];
    uint32_t hb = f2bf(w);
    uint32_t lb = f2bf(w - bf_lo(hb));
    int j = n >> 4, t = k >> 5, ln = (n & 15) | (((k >> 3) & 3) << 4), i = k & 7;
    int p = (j * 4 + t) * 512 + ln * 8 + i;
    hi[p] = (ushort)hb;
    lo[p] = (ushort)lb;
    return;
  }
  __shared__ int sh[NB];
  int t = threadIdx.x;
  for (int i = t; i < NB; i += 256) sh[i] = 0;
  __syncthreads();
  int base = blk * SCHUNK, lim = min(base + SCHUNK, E);
  for (int i = base + t; i < lim; i += 256) atomicAdd(&sh[dst[i] >> 7], 1);
  __syncthreads();
  for (int i = t; i < NB; i += 256) counts[i * nblk + blk] = sh[i];
}

// 2a) scan within 1024-blocks (coalesced, multi-block)
__global__ __launch_bounds__(1024) void k_scan1(const int* __restrict__ in, int* __restrict__ excl,
                                                int* __restrict__ blocksum, int n) {
  __shared__ int sd[1024];
  int tid = threadIdx.x;
  int i = blockIdx.x * 1024 + tid;
  int v = (i < n) ? in[i] : 0;
  int x = v;
  sd[tid] = x;
  __syncthreads();
  for (int off = 1; off < 1024; off <<= 1) {
    int t = (tid >= off) ? sd[tid - off] : 0;
    __syncthreads();
    x += t;
    sd[tid] = x;
    __syncthreads();
  }
  if (i < n) excl[i] = x - v;
  if (tid == 1023) blocksum[blockIdx.x] = x;
}

// 2b) scan block sums (1 block, 128 threads; nsb <= 128)
__global__ void k_scan2b(int* __restrict__ bs, int nb) {
  __shared__ int sh[128];
  int t = threadIdx.x;
  int v = (t < nb) ? bs[t] : 0;
  sh[t] = v;
  __syncthreads();
  for (int off = 1; off < 128; off <<= 1) {
    int add = (t >= off) ? sh[t - off] : 0;
    __syncthreads();
    sh[t] += add;
    __syncthreads();
  }
  if (t < nb) bs[t] = sh[t] - v;
}

// 2c) add block offsets in place; emit bbase[b] = excl[b*nblk], bbase[NB] = E
__global__ __launch_bounds__(256) void k_scan3b(int* __restrict__ excl, const int* __restrict__ boff,
                                                int* __restrict__ bbase, int total, int nblk, int E) {
  int i = blockIdx.x * 256 + threadIdx.x;
  if (i < total) {
    int val = excl[i] + boff[i >> 10];
    excl[i] = val;
    if (i % nblk == 0) bbase[i / nblk] = val;
  }
  if (i == 0) bbase[NB] = E;
}

// 3) scatter: block base from scanned counts, local rank via LDS atomics (no global atomics)
__global__ __launch_bounds__(256) void k_scatter3(const int* __restrict__ src, const int* __restrict__ dst,
                                                  const int* __restrict__ excl, uint32_t* __restrict__ packed,
                                                  int E, int nblk) {
  __shared__ int lcur[NB];
  int t = threadIdx.x, blk = blockIdx.x;
  for (int i = t; i < NB; i += 256) lcur[i] = excl[i * nblk + blk];
  __syncthreads();
  int base = blk * SCHUNK, lim = min(base + SCHUNK, E);
  for (int i = base + t; i < lim; i += 256) {
    int d = dst[i], s = src[i];
    int slot = atomicAdd(&lcur[d >> 7], 1);
    packed[slot] = (uint32_t)s | ((uint32_t)(d & 127) << 16);
  }
}

// 4) per-bucket local CSR build; emits csr_src, row_ptr, dinv
__global__ __launch_bounds__(256) void k_bucket(const uint32_t* __restrict__ packed, const int* __restrict__ bbase,
                                                int* __restrict__ csr_src, int* __restrict__ row_ptr,
                                                float* __restrict__ dinv, int N, int E, int nb) {
  __shared__ int hist[128];
  __shared__ int scan[128];
  __shared__ int cur[128];
  int b = blockIdx.x;
  int t = threadIdx.x;
  int base = bbase[b], end = bbase[b + 1];
  if (t < 128) hist[t] = 0;
  __syncthreads();
  for (int i = base + t; i < end; i += 256)
    atomicAdd(&hist[packed[i] >> 16], 1);
  __syncthreads();
  int v = (t < 128) ? hist[t] : 0;
  if (t < 128) scan[t] = v;
  __syncthreads();
  for (int off = 1; off < 128; off <<= 1) {
    int add = (t < 128 && t >= off) ? scan[t - off] : 0;
    __syncthreads();
    if (t < 128) scan[t] += add;
    __syncthreads();
  }
  if (t < 128) {
    int excl = scan[t] - v;
    cur[t] = excl;
    int node = b * 128 + t;
    if (node < N) {
      row_ptr[node] = base + excl;
      dinv[node] = rsqrtf((float)(v + 1));  // +1 self-loop
    }
    if (b == nb - 1 && t == 0) row_ptr[N] = E;
  }
  __syncthreads();
  for (int i = base + t; i < end; i += 256) {
    uint32_t p = packed[i];
    int slot = atomicAdd(&cur[p >> 16], 1);
    csr_src[base + slot] = (int)(p & 0xffffu);
  }
}

// ---------------- MFMA GEMM: h'[r] = (A[r] @ W) * dinv[r], bf16 out ----------------
__global__ __launch_bounds__(256) void k_gemm_mfma(const float* __restrict__ A,
                                                   const ushort* __restrict__ wpack,
                                                   const float* __restrict__ dinv,
                                                   ushort* __restrict__ Cp, int n) {
  const int lane = threadIdx.x & 63;
  const int gwave = (blockIdx.x * 256 + threadIdx.x) >> 6;
  const int rb = gwave * 32;
  if (rb >= n) return;
  const int lrow = lane & 15, lgrp = lane >> 4;
  const uint4* whi4 = (const uint4*)wpack;
  const uint4* wlo4 = (const uint4*)(wpack + 16384);

  const int r0 = rb + lrow, r1 = rb + 16 + lrow;
  const bool v0 = r0 < n, v1 = r1 < n;
  const int rc0 = v0 ? r0 : 0, rc1 = v1 ? r1 : 0;

  f32x4 acc0[8] = {};
  f32x4 acc1[8] = {};
  const uint4 zz = make_uint4(0, 0, 0, 0);

#pragma unroll
  for (int t = 0; t < 4; ++t) {
    FragU a0h, a0l, a1h, a1l;
    const float* ap0 = A + (size_t)rc0 * CH + t * 32 + lgrp * 8;
    const float* ap1 = A + (size_t)rc1 * CH + t * 32 + lgrp * 8;
    float4 xa = *(const float4*)ap0, xb = *(const float4*)(ap0 + 4);
    float4 ya = *(const float4*)ap1, yb = *(const float4*)(ap1 + 4);
    float xv[8] = {xa.x, xa.y, xa.z, xa.w, xb.x, xb.y, xb.z, xb.w};
    float yv[8] = {ya.x, ya.y, ya.z, ya.w, yb.x, yb.y, yb.z, yb.w};
#pragma unroll
    for (int i = 0; i < 8; ++i) {
      uint32_t h0 = f2bf(xv[i]);
      a0h.h[i] = (ushort)h0;
      a0l.h[i] = (ushort)f2bf(xv[i] - bf_lo(h0));
      uint32_t h1 = f2bf(yv[i]);
      a1h.h[i] = (ushort)h1;
      a1l.h[i] = (ushort)f2bf(yv[i] - bf_lo(h1));
    }
    if (!v0) { a0h.u = zz; a0l.u = zz; }
    if (!v1) { a1h.u = zz; a1l.u = zz; }
#pragma unroll
    for (int j = 0; j < 8; ++j) {
      FragU wh, wl;
      wh.u = whi4[(j * 4 + t) * 64 + lane];
      wl.u = wlo4[(j * 4 + t) * 64 + lane];
      acc0[j] = __builtin_amdgcn_mfma_f32_16x16x32_bf16(wh.s, a0h.s, acc0[j], 0, 0, 0);
      acc0[j] = __builtin_amdgcn_mfma_f32_16x16x32_bf16(wl.s, a0h.s, acc0[j], 0, 0, 0);
      acc0[j] = __builtin_amdgcn_mfma_f32_16x16x32_bf16(wh.s, a0l.s, acc0[j], 0, 0, 0);
      acc1[j] = __builtin_amdgcn_mfma_f32_16x16x32_bf16(wh.s, a1h.s, acc1[j], 0, 0, 0);
      acc1[j] = __builtin_amdgcn_mfma_f32_16x16x32_bf16(wl.s, a1h.s, acc1[j], 0, 0, 0);
      acc1[j] = __builtin_amdgcn_mfma_f32_16x16x32_bf16(wh.s, a1l.s, acc1[j], 0, 0, 0);
    }
  }

  if (v0) {
    float dv = dinv[r0];
#pragma unroll
    for (int j = 0; j < 8; ++j) {
      uint2 o;
      o.x = f2bf(acc0[j][0] * dv) | (f2bf(acc0[j][1] * dv) << 16);
      o.y = f2bf(acc0[j][2] * dv) | (f2bf(acc0[j][3] * dv) << 16);
      *(uint2*)&Cp[(size_t)r0 * CH + j * 16 + lgrp * 4] = o;
    }
  }
  if (v1) {
    float dv = dinv[r1];
#pragma unroll
    for (int j = 0; j < 8; ++j) {
      uint2 o;
      o.x = f2bf(acc1[j][0] * dv) | (f2bf(acc1[j][1] * dv) << 16);
      o.y = f2bf(acc1[j][2] * dv) | (f2bf(acc1[j][3] * dv) << 16);
      *(uint2*)&Cp[(size_t)r1 * CH + j * 16 + lgrp * 4] = o;
    }
  }
}

// ---------------- aggregation core: acc = h'[v] + sum_{s in N(v)} h'[s] ----------------
__device__ __forceinline__ void agg_node(const uint32_t* __restrict__ hp, const int* __restrict__ row_ptr,
                                         const int* __restrict__ csr, int v, int lane,
                                         float& a0, float& a1) {
  uint32_t self = hp[(size_t)v * 64 + lane];
  float acc0 = bf_lo(self), acc1 = bf_hi(self);
  int j = __builtin_amdgcn_readfirstlane(row_ptr[v]);
  int end = __builtin_amdgcn_readfirstlane(row_ptr[v + 1]);
  for (; j + 7 < end; j += 8) {
    int s[8];
#pragma unroll
    for (int k = 0; k < 8; ++k) s[k] = csr[j + k];
    uint32_t u[8];
#pragma unroll
    for (int k = 0; k < 8; ++k) u[k] = hp[(size_t)s[k] * 64 + lane];
#pragma unroll
    for (int k = 0; k < 8; ++k) { acc0 += bf_lo(u[k]); acc1 += bf_hi(u[k]); }
  }
  for (; j < end; ++j) {
    uint32_t u = hp[(size_t)csr[j] * 64 + lane];
    acc0 += bf_lo(u); acc1 += bf_hi(u);
  }
  a0 = acc0;
  a1 = acc1;
}

// ---------------- fused: agg1(+b1,relu) -> LDS -> @W2 -> h2' = h2*dinv (bf16) ----------------
// block = 256 threads = 4 waves; 32 nodes per block; LDS XOR-swizzled 32x128 bf16.
__global__ __launch_bounds__(256) void k_fused(const uint32_t* __restrict__ h1p, const int* __restrict__ row_ptr,
                                               const int* __restrict__ csr, const float* __restrict__ dinv,
                                               const float* __restrict__ b1,
                                               const ushort* __restrict__ wpack2,
                                               ushort* __restrict__ h2, int N) {
  __shared__ uint32_t sy[32 * 64];  // 32 rows x 128 bf16, word-swizzled
  const int w = threadIdx.x >> 6;
  const int lane = threadIdx.x & 63;
  const int vb = blockIdx.x * 32;
  float2 bb = *(const float2*)&b1[2 * lane];

  // ---- agg phase: each wave aggregates 8 nodes ----
  for (int q = 0; q < 8; ++q) {
    int lv = w * 8 + q;
    int v = vb + lv;
    uint32_t packed = 0;
    if (v < N) {
      float a0, a1;
      agg_node(h1p, row_ptr, csr, v, lane, a0, a1);
      float dv = dinv[v];
      float o0 = fmaxf(fmaf(dv, a0, bb.x), 0.f);
      float o1 = fmaxf(fmaf(dv, a1, bb.y), 0.f);
      packed = f2bf(o0) | (f2bf(o1) << 16);
    }
    sy[lv * 64 + (lane ^ ((lv & 7) << 2))] = packed;
  }
  __syncthreads();

  // ---- MFMA phase: 32x128 @ W2; wave w covers output cols [w*32, w*32+32) ----
  const int lrow = lane & 15, lgrp = lane >> 4;
  const uint4* whi4 = (const uint4*)wpack2;
  const uint4* wlo4 = (const uint4*)(wpack2 + 16384);

  FragU af[2][4];
#pragma unroll
  for (int rt = 0; rt < 2; ++rt) {
#pragma unroll
    for (int t = 0; t < 4; ++t) {
      int row = rt * 16 + lrow;
      int grp = (t * 4 + lgrp) ^ (row & 7);
      af[rt][t].u = *(const uint4*)&sy[row * 64 + grp * 4];
    }
  }

  f32x4 acc[2][2] = {};
#pragma unroll
  for (int jj = 0; jj < 2; ++jj) {
    int j = w * 2 + jj;
#pragma unroll
    for (int t = 0; t < 4; ++t) {
      FragU wh, wl;
      wh.u = whi4[(j * 4 + t) * 64 + lane];
      wl.u = wlo4[(j * 4 + t) * 64 + lane];
      acc[0][jj] = __builtin_amdgcn_mfma_f32_16x16x32_bf16(wh.s, af[0][t].s, acc[0][jj], 0, 0, 0);
      acc[0][jj] = __builtin_amdgcn_mfma_f32_16x16x32_bf16(wl.s, af[0][t].s, acc[0][jj], 0, 0, 0);
      acc[1][jj] = __builtin_amdgcn_mfma_f32_16x16x32_bf16(wh.s, af[1][t].s, acc[1][jj], 0, 0, 0);
      acc[1][jj] = __builtin_amdgcn_mfma_f32_16x16x32_bf16(wl.s, af[1][t].s, acc[1][jj], 0, 0, 0);
    }
  }

#pragma unroll
  for (int rt = 0; rt < 2; ++rt) {
    int r = vb + rt * 16 + lrow;
    if (r < N) {
      float dvr = dinv[r];
#pragma unroll
      for (int jj = 0; jj < 2; ++jj) {
        int j = w * 2 + jj;
        uint2 o;
        o.x = f2bf(acc[rt][jj][0] * dvr) | (f2bf(acc[rt][jj][1] * dvr) << 16);
        o.y = f2bf(acc[rt][jj][2] * dvr) | (f2bf(acc[rt][jj][3] * dvr) << 16);
        *(uint2*)&h2[(size_t)r * CH + j * 16 + lgrp * 4] = o;
      }
    }
  }
}

// ---------------- final aggregation: out[v] = relu(dv * (sum h2'[s] + h2'[v]) + b2), fp32 ----
__global__ __launch_bounds__(256) void k_agg2(const uint32_t* __restrict__ h2p, const int* __restrict__ row_ptr,
                                              const int* __restrict__ csr, const float* __restrict__ dinv,
                                              const float* __restrict__ b2, float* __restrict__ out, int n) {
  int v = (blockIdx.x * 256 + threadIdx.x) >> 6;
  int lane = threadIdx.x & 63;
  if (v >= n) return;
  v = __builtin_amdgcn_readfirstlane(v);
  float a0, a1;
  agg_node(h2p, row_ptr, csr, v, lane, a0, a1);
  float dv = dinv[v];
  float2 bb = *(const float2*)&b2[2 * lane];
  float o0 = fmaxf(fmaf(dv, a0, bb.x), 0.f);
  float o1 = fmaxf(fmaf(dv, a1, bb.y), 0.f);
  ((float2*)out)[(size_t)v * 64 + lane] = make_float2(o0, o1);
}

// ---------------- launch ----------------

extern "C" void kernel_launch(void* const* d_in, const int* in_sizes, int n_in,
                              void* d_out, int out_size, void* d_ws, size_t ws_size,
                              hipStream_t stream) {
  const float* x  = (const float*)d_in[0];
  const int*   ei = (const int*)d_in[1];
  const float* W1 = (const float*)d_in[2];
  const float* b1 = (const float*)d_in[3];
  const float* W2 = (const float*)d_in[4];
  const float* b2 = (const float*)d_in[5];
  float* out = (float*)d_out;

  const int N = in_sizes[0] / CH;
  const int E = in_sizes[1] / 2;
  const int* src = ei;
  const int* dst = ei + E;
  const int nb = (N + 127) / 128;              // used coarse buckets (<= NB)
  const int nblk = (E + SCHUNK - 1) / SCHUNK;  // hist/scatter blocks
  const int total = NB * nblk;                 // counts array size
  const int nsb = (total + 1023) / 1024;       // scan blocks (<=128)

  char* ws = (char*)d_ws;
  size_t off = 0;
  auto alloc = [&](size_t bytes) -> void* {
    void* p = ws + off;
    off += (bytes + 255) & ~(size_t)255;
    return p;
  };
  int*      counts  = (int*)alloc((size_t)total * 4);     // scanned in place
  int*      blocksum= (int*)alloc(128 * 4);
  int*      bbase   = (int*)alloc((NB + 1) * 4);
  uint32_t* packed  = (uint32_t*)alloc((size_t)E * 4);
  int*      row_ptr = (int*)alloc((size_t)(N + 1) * 4);
  int*      csr_src = (int*)alloc((size_t)E * 4);
  float*    dinv    = (float*)alloc((size_t)N * 4);
  ushort*   wpack   = (ushort*)alloc(4 * 16384 * 2);       // [hi1|lo1|hi2|lo2]
  ushort*   h1      = (ushort*)alloc((size_t)N * CH * 2);  // bf16, dinv-scaled
  ushort*   h2      = (ushort*)alloc((size_t)N * CH * 2);  // bf16, dinv-scaled
  (void)ws_size;

  k_histw<<<nblk + 128, 256, 0, stream>>>(dst, counts, E, nblk, W1, W2, wpack);
  k_scan1<<<nsb, 1024, 0, stream>>>(counts, counts, blocksum, total);
  k_scan2b<<<1, 128, 0, stream>>>(blocksum, nsb);
  k_scan3b<<<(total + 255) / 256, 256, 0, stream>>>(counts, blocksum, bbase, total, nblk, E);
  k_scatter3<<<nblk, 256, 0, stream>>>(src, dst, counts, packed, E, nblk);
  k_bucket<<<nb, 256, 0, stream>>>(packed, bbase, csr_src, row_ptr, dinv, N, E, nb);

  const int waves = (N + 31) / 32;
  const int gG = (waves + 3) / 4;
  const int gF = (N + 31) / 32;
  const int gA = (N + 3) / 4;

  k_gemm_mfma<<<gG, 256, 0, stream>>>(x, wpack, dinv, h1, N);
  k_fused<<<gF, 256, 0, stream>>>((const uint32_t*)h1, row_ptr, csr_src, dinv, b1,
                                  wpack + 32768, h2, N);
  k_agg2<<<gA, 256, 0, stream>>>((const uint32_t*)h2, row_ptr, csr_src, dinv, b2, out, N);
}